// Round 9
// baseline (133.981 us; speedup 1.0000x reference)
//
#include <hip/hip_runtime.h>
#include <hip/hip_fp16.h>

#define D_VOCAB 262
#define D_EMB   128
#define KW      5
#define NCHAR   16
#define NKO     (KW * D_EMB)      // 640 halfs per vocab row (1280 B)

typedef _Float16 h8 __attribute__((ext_vector_type(8)));
typedef float    f8 __attribute__((ext_vector_type(8)));

// d_ws layout: P at offset 0: 262*640 halfs = 335,360 B (fp16, P[v][k][o])

// ---------------------------------------------------------------------------
// Fused precompute: P[v][k][o] = sum_i emb[v][i] * conv_w[o][i][k], fp16.
// One block per v, 640 threads with t -> (o = t/5, k = t%5) so that for each
// i the wave's 64 lanes touch ~13 consecutive-ish 64B lines (20 B per o-chunk)
// instead of 64 scattered lines with the o-major mapping. emb row staged in
// LDS (broadcast reads). P write is a 1280 B scatter per block - negligible.
// 262 blocks x 10 waves, no inner barriers. ~4 us.
// ---------------------------------------------------------------------------
__global__ __launch_bounds__(640) void precompute_P_kernel(
    const float* __restrict__ emb, const float* __restrict__ cw,
    __half* __restrict__ P) {
  __shared__ float emb_s[D_EMB];
  const int v = blockIdx.x;
  const int t = threadIdx.x;            // 0..639
  if (t < D_EMB) emb_s[t] = emb[v * D_EMB + t];
  __syncthreads();

  const int o = t / KW;
  const int k = t - o * KW;
  const float* w = cw + o * (D_EMB * KW) + k;   // stride 5 floats over i
  float acc = 0.f;
#pragma unroll 16
  for (int i = 0; i < D_EMB; ++i) {
    acc += emb_s[i] * w[i * KW];
  }
  P[v * NKO + k * D_EMB + o] = __float2half(acc);
}

// ---------------------------------------------------------------------------
// Main: 4 seqs/wave, 16 lanes/seq, 8 channels/lane. Per (j,k) tap: ONE 16 B
// load (8 halfs) + 4x v_pk_add_f16 into a rolling 5-slot window; packed max
// at slot completion. No LDS, no barriers. __launch_bounds__(256,8) clamps
// VGPR to 64 for 8 waves/SIMD (structure is L1-latency bound; more resident
// waves = more outstanding loads). Revert to (256) if this spills.
// ---------------------------------------------------------------------------
__global__ __launch_bounds__(256, 8) void conv_char_main_kernel(
    const int* __restrict__ ids, const _Float16* __restrict__ P,
    const float* __restrict__ bias, float* __restrict__ out) {
  const int lane = threadIdx.x & 63;
  const int wave = threadIdx.x >> 6;
  const int n_base = (blockIdx.x * 4 + wave) * 4;  // 4 seqs per wave
  const int g4 = lane & 48;                        // seq-group * 16
  const int s = lane & 15;
  const int o = s * 8;                             // this lane's 8 channels
  const int n = n_base + (lane >> 4);

  // the wave's 64 ids (4 seqs x 16 chars), coalesced
  const int myid = ids[n_base * NCHAR + lane];

  h8 win[5];
#pragma unroll
  for (int w = 0; w < 5; ++w) win[w] = (h8)(_Float16)0.f;
  h8 vmax = (h8)(_Float16)(-60000.f);

#pragma unroll
  for (int j = 0; j < NCHAR; ++j) {
    const int id = __shfl(myid, g4 + j);           // broadcast within group
    const _Float16* row = P + (size_t)id * NKO + o;
#pragma unroll
    for (int k = 0; k < KW; ++k) {
      const int c = j + 2 - k;                     // output position fed
      if (c >= 0 && c < NCHAR) {
        const h8 val = *(const h8*)(row + k * D_EMB);   // 16 B load
        win[c % 5] += val;                              // 4x v_pk_add_f16
      }
    }
    if (j >= 2) {                                  // y[j-2] complete
      const int w = (j - 2) % 5;
      vmax = __builtin_elementwise_max(vmax, win[w]);   // 4x v_pk_max_f16
      win[w] = (h8)(_Float16)0.f;
    }
  }
  vmax = __builtin_elementwise_max(vmax, win[14 % 5]);
  vmax = __builtin_elementwise_max(vmax, win[15 % 5]);

  const f8 fv = __builtin_convertvector(vmax, f8);
  const f8 bv = *(const f8*)(bias + o);
  const f8 r = fv + bv;
  *(f8*)(out + (size_t)n * D_EMB + o) = r;
}

// ---------------------------------------------------------------------------
// Inputs: d_in[0] ids (B*W*C int32), d_in[1] lengths (unused),
//         d_in[2] emb (262x128 f32), d_in[3] conv_w (128x128x5 f32),
//         d_in[4] conv_b (128 f32).  Output: (B*W*128) f32.
// ---------------------------------------------------------------------------
extern "C" void kernel_launch(void* const* d_in, const int* in_sizes, int n_in,
                              void* d_out, int out_size, void* d_ws, size_t ws_size,
                              hipStream_t stream) {
  const int*   input = (const int*)d_in[0];
  const float* emb   = (const float*)d_in[2];
  const float* cw    = (const float*)d_in[3];
  const float* cb    = (const float*)d_in[4];
  float* out = (float*)d_out;

  _Float16* P = (_Float16*)d_ws;

  const int n_seq = in_sizes[0] / NCHAR;   // B*W = 32768

  precompute_P_kernel<<<D_VOCAB, 640, 0, stream>>>(emb, cw, (__half*)P);

  const int blocks = n_seq / 16;           // 4 waves/block, 4 seqs/wave
  conv_char_main_kernel<<<blocks, 256, 0, stream>>>(input, P, cb, out);
}

// Round 10
// 95.040 us; speedup vs baseline: 1.4097x; 1.4097x over previous
//
#include <hip/hip_runtime.h>
#include <hip/hip_fp16.h>

#define D_VOCAB 262
#define D_EMB   128
#define KW      5
#define NCHAR   16
#define NKO     (KW * D_EMB)      // 640 halfs per vocab row (1280 B)

typedef _Float16 h8 __attribute__((ext_vector_type(8)));
typedef float    f8 __attribute__((ext_vector_type(8)));

// d_ws layout:
//   P   at offset 0       : 262*640 halfs = 335,360 B (fp16 table, P[v][k][o])
//   Wt2 at offset 335,872 : 128*640 floats = 327,680 B, Wt2[i][ko]

// ---------------------------------------------------------------------------
// Stage 1: Wt2[i*640 + k*128 + o] = conv_w[o*640 + i*5 + k]. Coalesced dword
// reads, scattered dword writes (320 KB, L2 absorbs). No LDS/barriers. ~2 us.
// ---------------------------------------------------------------------------
__global__ __launch_bounds__(256) void transpose_w_kernel(
    const float* __restrict__ cw, float* __restrict__ Wt2) {
  const int gid = blockIdx.x * 256 + threadIdx.x;   // 0..81919
  const float val = cw[gid];
  const int o = gid / 640;
  const int r = gid - o * 640;
  const int i = r / 5;
  const int k = r - i * 5;
  Wt2[i * NKO + k * D_EMB + o] = val;
}

// ---------------------------------------------------------------------------
// Stage 2: P[v][k*128+o] = sum_i emb[v][i] * Wt2[i][k*128+o], fp16.
// Block = (v,k) pair (1310 blocks x 128 threads, t = o): lane-consecutive
// dword reads of L2-resident Wt2 (fully coalesced), emb row in LDS.
// vs R8's 262x640: same instructions, but 5.1 small blocks/CU instead of
// 1.02 ten-wave blocks/CU -> no double-block CU tail. ~4-5 us.
// ---------------------------------------------------------------------------
__global__ __launch_bounds__(128) void compute_P_kernel(
    const float* __restrict__ emb, const float* __restrict__ Wt2,
    __half* __restrict__ P) {
  __shared__ float emb_s[D_EMB];
  const int b = blockIdx.x;             // 0..1309
  const int v = b / KW;
  const int k = b - v * KW;
  const int t = threadIdx.x;            // o
  emb_s[t] = emb[v * D_EMB + t];
  __syncthreads();

  const float* col = Wt2 + k * D_EMB + t;
  float acc = 0.f;
#pragma unroll 16
  for (int i = 0; i < D_EMB; ++i) {
    acc += emb_s[i] * col[i * NKO];
  }
  P[v * NKO + k * D_EMB + t] = __float2half(acc);
}

// ---------------------------------------------------------------------------
// Main (R8 config - fastest measured, ~28 us, at its L1-BW floor):
// 4 seqs/wave, 16 lanes/seq, 8 channels/lane. Per (j,k) tap: ONE 16 B load
// (8 halfs) + 4x v_pk_add_f16 into a rolling 5-slot window; packed max at
// slot completion. No LDS, no barriers, NO min-waves clamp (R9's (256,8)
// capped VGPR at 64 -> spilled the in-flight loads, +25 us).
// ---------------------------------------------------------------------------
__global__ __launch_bounds__(256) void conv_char_main_kernel(
    const int* __restrict__ ids, const _Float16* __restrict__ P,
    const float* __restrict__ bias, float* __restrict__ out) {
  const int lane = threadIdx.x & 63;
  const int wave = threadIdx.x >> 6;
  const int n_base = (blockIdx.x * 4 + wave) * 4;  // 4 seqs per wave
  const int g4 = lane & 48;                        // seq-group * 16
  const int s = lane & 15;
  const int o = s * 8;                             // this lane's 8 channels
  const int n = n_base + (lane >> 4);

  // the wave's 64 ids (4 seqs x 16 chars), coalesced
  const int myid = ids[n_base * NCHAR + lane];

  h8 win[5];
#pragma unroll
  for (int w = 0; w < 5; ++w) win[w] = (h8)(_Float16)0.f;
  h8 vmax = (h8)(_Float16)(-60000.f);

#pragma unroll
  for (int j = 0; j < NCHAR; ++j) {
    const int id = __shfl(myid, g4 + j);           // broadcast within group
    const _Float16* row = P + (size_t)id * NKO + o;
#pragma unroll
    for (int k = 0; k < KW; ++k) {
      const int c = j + 2 - k;                     // output position fed
      if (c >= 0 && c < NCHAR) {
        const h8 val = *(const h8*)(row + k * D_EMB);   // 16 B load
        win[c % 5] += val;                              // 4x v_pk_add_f16
      }
    }
    if (j >= 2) {                                  // y[j-2] complete
      const int w = (j - 2) % 5;
      vmax = __builtin_elementwise_max(vmax, win[w]);   // 4x v_pk_max_f16
      win[w] = (h8)(_Float16)0.f;
    }
  }
  vmax = __builtin_elementwise_max(vmax, win[14 % 5]);
  vmax = __builtin_elementwise_max(vmax, win[15 % 5]);

  const f8 fv = __builtin_convertvector(vmax, f8);
  const f8 bv = *(const f8*)(bias + o);
  const f8 r = fv + bv;
  *(f8*)(out + (size_t)n * D_EMB + o) = r;
}

// ---------------------------------------------------------------------------
// Inputs: d_in[0] ids (B*W*C int32), d_in[1] lengths (unused),
//         d_in[2] emb (262x128 f32), d_in[3] conv_w (128x128x5 f32),
//         d_in[4] conv_b (128 f32).  Output: (B*W*128) f32.
// ---------------------------------------------------------------------------
extern "C" void kernel_launch(void* const* d_in, const int* in_sizes, int n_in,
                              void* d_out, int out_size, void* d_ws, size_t ws_size,
                              hipStream_t stream) {
  const int*   input = (const int*)d_in[0];
  const float* emb   = (const float*)d_in[2];
  const float* cw    = (const float*)d_in[3];
  const float* cb    = (const float*)d_in[4];
  float* out = (float*)d_out;

  _Float16* P   = (_Float16*)d_ws;
  float*    Wt2 = (float*)((char*)d_ws + 335872);

  const int n_seq = in_sizes[0] / NCHAR;   // B*W = 32768

  transpose_w_kernel<<<320, 256, 0, stream>>>(cw, Wt2);          // 81,920 elems
  compute_P_kernel<<<D_VOCAB * KW, 128, 0, stream>>>(emb, Wt2, (__half*)P);

  const int blocks = n_seq / 16;           // 4 waves/block, 4 seqs/wave
  conv_char_main_kernel<<<blocks, 256, 0, stream>>>(input, P, cb, out);
}

// Round 11
// 93.675 us; speedup vs baseline: 1.4303x; 1.0146x over previous
//
#include <hip/hip_runtime.h>
#include <hip/hip_fp16.h>

#define D_VOCAB 262
#define D_EMB   128
#define KW      5
#define NCHAR   16
#define NKO     (KW * D_EMB)      // 640 halfs per vocab row (1280 B)

typedef _Float16 h2 __attribute__((ext_vector_type(2)));
typedef _Float16 h8 __attribute__((ext_vector_type(8)));

// d_ws layout:
//   P   at offset 0       : 262*640 halfs = 335,360 B (fp16 table, P[v][k][o])
//   Wt2 at offset 335,872 : 128*640 floats = 327,680 B, Wt2[i][ko]

// ---------------------------------------------------------------------------
// Stage 1: Wt2[i*640 + k*128 + o] = conv_w[o*640 + i*5 + k]. Coalesced dword
// reads, scattered dword writes (320 KB, L2 absorbs). ~2 us.
// ---------------------------------------------------------------------------
__global__ __launch_bounds__(256) void transpose_w_kernel(
    const float* __restrict__ cw, float* __restrict__ Wt2) {
  const int gid = blockIdx.x * 256 + threadIdx.x;   // 0..81919
  const float val = cw[gid];
  const int o = gid / 640;
  const int r = gid - o * 640;
  const int i = r / 5;
  const int k = r - i * 5;
  Wt2[i * NKO + k * D_EMB + o] = val;
}

// ---------------------------------------------------------------------------
// Stage 2: P[v][k*128+o] = sum_i emb[v][i] * Wt2[i][k*128+o], fp16.
// Block = (v,k) (1310 x 128, t = o): lane-consecutive dword reads of
// L2-resident Wt2 (fully coalesced), emb row in LDS. ~4-5 us (R10-measured).
// ---------------------------------------------------------------------------
__global__ __launch_bounds__(128) void compute_P_kernel(
    const float* __restrict__ emb, const float* __restrict__ Wt2,
    __half* __restrict__ P) {
  __shared__ float emb_s[D_EMB];
  const int b = blockIdx.x;             // 0..1309
  const int v = b / KW;
  const int k = b - v * KW;
  const int t = threadIdx.x;            // o
  emb_s[t] = emb[v * D_EMB + t];
  __syncthreads();

  const float* col = Wt2 + k * D_EMB + t;
  float acc = 0.f;
#pragma unroll 16
  for (int i = 0; i < D_EMB; ++i) {
    acc += emb_s[i] * col[i * NKO];
  }
  P[v * NKO + k * D_EMB + t] = __float2half(acc);
}

// ---------------------------------------------------------------------------
// Main: 1 seq/wave, 2 channels/lane. Measured-best addressing (R0-v0):
// wave-uniform seq index via readfirstlane -> ids come in as SCALAR s_loads,
// P row base lives in SGPRs, each (j,k) tap is ONE dword load covering a
// single 256 B k-row (one 4-line segment; k folds into the imm offset).
// v0's fp32 tail (12 VALU/tap) replaced by 1x v_pk_add_f16 into a rolling
// 5-slot __half2 window + v_pk_max_f16 at slot completion. ~35 VGPR ->
// 8 waves/SIMD natural occupancy (no clamp, nothing to spill).
// ---------------------------------------------------------------------------
__global__ __launch_bounds__(256) void conv_char_main_kernel(
    const int* __restrict__ ids, const _Float16* __restrict__ P,
    const float* __restrict__ bias, float* __restrict__ out) {
  const int lane = threadIdx.x & 63;
  int n = (int)((blockIdx.x * 256 + threadIdx.x) >> 6);
  n = __builtin_amdgcn_readfirstlane(n);   // wave-uniform sequence index

  const int* idrow = ids + n * NCHAR;
  const int o = lane * 2;                  // this lane's 2 channels

  h2 win[5];
#pragma unroll
  for (int w = 0; w < 5; ++w) win[w] = (h2)(_Float16)0.f;
  h2 vmax = (h2)(_Float16)(-60000.f);

#pragma unroll
  for (int j = 0; j < NCHAR; ++j) {
    const int id = idrow[j];               // scalar (SMEM) load, uniform
    const _Float16* row = P + (size_t)id * NKO + o;
#pragma unroll
    for (int k = 0; k < KW; ++k) {
      const int c = j + 2 - k;             // output position fed
      if (c >= 0 && c < NCHAR) {
        const h2 val = *(const h2*)(row + k * D_EMB);  // dword, imm offset
        win[c % 5] += val;                             // v_pk_add_f16
      }
    }
    if (j >= 2) {                          // y[j-2] complete
      const int w = (j - 2) % 5;
      vmax = __builtin_elementwise_max(vmax, win[w]);  // v_pk_max_f16
      win[w] = (h2)(_Float16)0.f;
    }
  }
  vmax = __builtin_elementwise_max(vmax, win[14 % 5]);
  vmax = __builtin_elementwise_max(vmax, win[15 % 5]);

  const float2 bv = *(const float2*)(bias + o);
  float2 r;
  r.x = (float)vmax.x + bv.x;
  r.y = (float)vmax.y + bv.y;
  *(float2*)(out + (size_t)n * D_EMB + o) = r;   // 512 B/wave, coalesced
}

// ---------------------------------------------------------------------------
// Inputs: d_in[0] ids (B*W*C int32), d_in[1] lengths (unused),
//         d_in[2] emb (262x128 f32), d_in[3] conv_w (128x128x5 f32),
//         d_in[4] conv_b (128 f32).  Output: (B*W*128) f32.
// ---------------------------------------------------------------------------
extern "C" void kernel_launch(void* const* d_in, const int* in_sizes, int n_in,
                              void* d_out, int out_size, void* d_ws, size_t ws_size,
                              hipStream_t stream) {
  const int*   input = (const int*)d_in[0];
  const float* emb   = (const float*)d_in[2];
  const float* cw    = (const float*)d_in[3];
  const float* cb    = (const float*)d_in[4];
  float* out = (float*)d_out;

  _Float16* P   = (_Float16*)d_ws;
  float*    Wt2 = (float*)((char*)d_ws + 335872);

  const int n_seq = in_sizes[0] / NCHAR;   // B*W = 32768

  transpose_w_kernel<<<320, 256, 0, stream>>>(cw, Wt2);          // 81,920 elems
  compute_P_kernel<<<D_VOCAB * KW, 128, 0, stream>>>(emb, Wt2, (__half*)P);

  const int blocks = n_seq / 4;            // 1 seq/wave, 4 waves/block
  conv_char_main_kernel<<<blocks, 256, 0, stream>>>(input, P, cb, out);
}